// Round 1
// baseline (333.409 us; speedup 1.0000x reference)
//
#include <hip/hip_runtime.h>
#include <hip/hip_bf16.h>

// TritonDynamicAttention: blocksparse causal attention, B=2,H=16,S=2048,D=64, BLOCK=32.
// Plan: (1) split K into bf16 hi/lo, (2) exact block-mask with bias>0 and causal skips,
// (3) flash attention with 16x16x32 bf16 MFMA, QK^T in hi/lo split for accuracy.

typedef __bf16 bf16_t;
typedef bf16_t bf16x8 __attribute__((ext_vector_type(8)));
typedef float  f32x4  __attribute__((ext_vector_type(4)));
typedef int    i32x4  __attribute__((ext_vector_type(4)));

constexpr int Bc = 2, Hc = 16, Sc = 2048, Dc = 64;
constexpr int NB = Sc / 32;                       // 64 mask blocks per side
constexpr size_t QKV_ELEMS = (size_t)Bc * Hc * Sc * Dc;   // 4194304
constexpr int VTS  = 40;   // LDS V^T row stride (bf16 elems): 80B, 16B-aligned, bank-friendly
constexpr int PSTR = 40;   // LDS P row stride

__device__ inline f32x4 mfma16(bf16x8 a, bf16x8 b, f32x4 c) {
    return __builtin_amdgcn_mfma_f32_16x16x32_bf16(a, b, c, 0, 0, 0);
}

// ---------- kernel 1: K fp32 -> (Kh, Kl) bf16 split ----------
__global__ __launch_bounds__(256) void k_convert(const float* __restrict__ k,
                                                 bf16_t* __restrict__ kh,
                                                 bf16_t* __restrict__ kl) {
    size_t i = ((size_t)blockIdx.x * 256 + threadIdx.x) * 8;
    f32x4 a = *(const f32x4*)(k + i);
    f32x4 b = *(const f32x4*)(k + i + 4);
    float xs[8] = {a[0], a[1], a[2], a[3], b[0], b[1], b[2], b[3]};
    bf16x8 h, l;
#pragma unroll
    for (int j = 0; j < 8; j++) {
        bf16_t hh = (bf16_t)xs[j];
        h[j] = hh;
        l[j] = (bf16_t)(xs[j] - (float)hh);
    }
    *(bf16x8*)(kh + i) = h;
    *(bf16x8*)(kl + i) = l;
}

// ---------- kernel 2: block mask ----------
// bm[h][br][bc] = (sum(mask block) + bias[h]) > 0.  Only bc <= br is ever read later
// (causal), and bias>0 heads are always-active (block sums are >= 0).
__global__ __launch_bounds__(256) void k_blockmask(const int* __restrict__ mask,
                                                   const float* __restrict__ bias,
                                                   unsigned char* __restrict__ bm) {
    int h  = blockIdx.x / NB;
    int br = blockIdx.x % NB;
    float bv = bias[h];
    unsigned char* outp = bm + ((size_t)h * NB + br) * NB;
    int t = threadIdx.x;
    if (bv > 0.f) {
        if (t < NB) outp[t] = 1;
        return;
    }
    int bc0 = t >> 3;        // 0..31  (thread covers cols 4t..4t+3)
    int bc1 = 32 + bc0;      // 32..63 (cols 1024+4t..)
    const int* base = mask + ((size_t)h * Sc + (size_t)br * 32) * (size_t)Sc;
    int acc0 = 0, acc1 = 0;
    bool d0 = (bc0 <= br), d1 = (bc1 <= br);
    if (d0) {
        const int* p = base + 4 * t;
#pragma unroll 8
        for (int r = 0; r < 32; r++) {
            i32x4 v = *(const i32x4*)(p + (size_t)r * Sc);
            acc0 += v[0] + v[1] + v[2] + v[3];
        }
    }
    if (d1) {
        const int* p = base + 1024 + 4 * t;
#pragma unroll 8
        for (int r = 0; r < 32; r++) {
            i32x4 v = *(const i32x4*)(p + (size_t)r * Sc);
            acc1 += v[0] + v[1] + v[2] + v[3];
        }
    }
#pragma unroll
    for (int off = 1; off < 8; off <<= 1) {
        acc0 += __shfl_xor(acc0, off);
        acc1 += __shfl_xor(acc1, off);
    }
    if ((t & 7) == 0) {
        if (d0) outp[bc0] = ((float)acc0 + bv > 0.f) ? 1 : 0;
        if (d1) outp[bc1] = ((float)acc1 + bv > 0.f) ? 1 : 0;
    }
}

// ---------- kernel 3: flash blocksparse causal attention ----------
// Grid: B*H*(S/64) workgroups of 256 (4 waves). Wave w owns 16 q-rows.
// KV iterated in 32-blocks (mask granularity). QK^T = (Qh+Ql)(Kh+Kl) 3-term split.
__global__ __launch_bounds__(256) void k_attn(const float* __restrict__ Q,
                                              const float* __restrict__ V,
                                              const bf16_t* __restrict__ KH,
                                              const bf16_t* __restrict__ KL,
                                              const unsigned char* __restrict__ BM,
                                              float* __restrict__ Out) {
    __shared__ bf16_t vt[64 * VTS];        // V^T tile: [d][kv], kv-block of 32
    __shared__ bf16_t pl[4 * 16 * PSTR];   // per-wave P tile [16][32]

    const int qblk = blockIdx.x & 31;      // S/64 = 32 q-blocks
    const int bh   = blockIdx.x >> 5;      // b*H + h
    const int h    = bh & (Hc - 1);
    const int tid  = threadIdx.x;
    const int w    = tid >> 6, lane = tid & 63;
    const int l16  = lane & 15, lg = lane >> 4;

    const size_t bh_off = (size_t)bh * Sc * Dc;
    const float* q_ptr  = Q + bh_off;
    const float* v_ptr  = V + bh_off;
    const bf16_t* khp   = KH + bh_off;
    const bf16_t* klp   = KL + bh_off;

    const int q0   = qblk * 64 + w * 16;   // first q-row of this wave
    const int brow = q0 >> 5;              // mask block-row
    const unsigned char* bmrow = BM + ((size_t)h * NB + brow) * NB;

    // Q fragments (A-operand): lane holds Q[q0 + l16][ks*32 + lg*8 + j]
    bf16x8 qh[2], ql[2];
    {
        const float* qr = q_ptr + (size_t)(q0 + l16) * Dc + lg * 8;
#pragma unroll
        for (int ks = 0; ks < 2; ks++) {
            f32x4 a = *(const f32x4*)(qr + ks * 32);
            f32x4 b = *(const f32x4*)(qr + ks * 32 + 4);
            float xs[8] = {a[0], a[1], a[2], a[3], b[0], b[1], b[2], b[3]};
#pragma unroll
            for (int j = 0; j < 8; j++) {
                bf16_t hh = (bf16_t)xs[j];
                qh[ks][j] = hh;
                ql[ks][j] = (bf16_t)(xs[j] - (float)hh);
            }
        }
    }

    f32x4 o[4];
    float mrow[4], lrow[4];
#pragma unroll
    for (int n = 0; n < 4; n++) { o[n][0] = 0.f; o[n][1] = 0.f; o[n][2] = 0.f; o[n][3] = 0.f; }
#pragma unroll
    for (int r = 0; r < 4; r++) { mrow[r] = -1e30f; lrow[r] = 0.f; }

    const int kbmax = qblk * 2 + 1;
    for (int kb = 0; kb <= kbmax; kb++) {
        // ---- stage V tile (fp32 -> bf16, transposed) ----
        {
            int kv = tid & 31, dg = tid >> 5;   // dg 0..7
            const float* vr = v_ptr + (size_t)(kb * 32 + kv) * Dc + dg * 8;
            f32x4 a = *(const f32x4*)vr;
            f32x4 b = *(const f32x4*)(vr + 4);
            float xs[8] = {a[0], a[1], a[2], a[3], b[0], b[1], b[2], b[3]};
#pragma unroll
            for (int j = 0; j < 8; j++) vt[(dg * 8 + j) * VTS + kv] = (bf16_t)xs[j];
        }
        __syncthreads();

        bool active = (kb <= brow) && (bmrow[kb] != 0);
        if (active) {
            // K fragments (B-operand): lane holds K[kb*32 + 16t + l16][ks*32 + lg*8 + j]
            bf16x8 kwh[2][2], kwl[2][2];
#pragma unroll
            for (int t = 0; t < 2; t++) {
                size_t kro = (size_t)(kb * 32 + t * 16 + l16) * Dc + lg * 8;
#pragma unroll
                for (int ks = 0; ks < 2; ks++) {
                    kwh[t][ks] = *(const bf16x8*)(khp + kro + ks * 32);
                    kwl[t][ks] = *(const bf16x8*)(klp + kro + ks * 32);
                }
            }
            f32x4 s0, s1;
            s0[0] = s0[1] = s0[2] = s0[3] = 0.f;
            s1[0] = s1[1] = s1[2] = s1[3] = 0.f;
#pragma unroll
            for (int ks = 0; ks < 2; ks++) {
                s0 = mfma16(qh[ks], kwh[0][ks], s0);
                s1 = mfma16(qh[ks], kwh[1][ks], s1);
                s0 = mfma16(qh[ks], kwl[0][ks], s0);
                s1 = mfma16(qh[ks], kwl[1][ks], s1);
                s0 = mfma16(ql[ks], kwh[0][ks], s0);
                s1 = mfma16(ql[ks], kwh[1][ks], s1);
            }
            // causal elementwise mask (only possible on the diagonal mask block)
            if (kb == brow) {
#pragma unroll
                for (int r = 0; r < 4; r++) {
                    int rowg = q0 + lg * 4 + r;
                    int c0   = kb * 32 + l16;
                    if (c0 > rowg)      s0[r] = -1e30f;
                    if (c0 + 16 > rowg) s1[r] = -1e30f;
                }
            }
            // online softmax: row r stats live in all 16 lanes of the lg-group
            float p0[4], p1[4], alpha[4];
#pragma unroll
            for (int r = 0; r < 4; r++) {
                float mx = fmaxf(s0[r], s1[r]);
#pragma unroll
                for (int off = 1; off < 16; off <<= 1) mx = fmaxf(mx, __shfl_xor(mx, off));
                float mn = fmaxf(mrow[r], mx);
                float al = __expf(mrow[r] - mn);
                mrow[r] = mn;
                float e0 = __expf(s0[r] - mn), e1 = __expf(s1[r] - mn);
                p0[r] = e0; p1[r] = e1;
                float rs = e0 + e1;
#pragma unroll
                for (int off = 1; off < 16; off <<= 1) rs += __shfl_xor(rs, off);
                lrow[r] = lrow[r] * al + rs;
                alpha[r] = al;
            }
#pragma unroll
            for (int n = 0; n < 4; n++) {
#pragma unroll
                for (int r = 0; r < 4; r++) o[n][r] *= alpha[r];
            }
            // P -> LDS (score layout -> A-frag layout)
            bf16_t* pw = pl + w * 16 * PSTR;
#pragma unroll
            for (int r = 0; r < 4; r++) {
                int row = lg * 4 + r;
                pw[row * PSTR + l16]      = (bf16_t)p0[r];
                pw[row * PSTR + 16 + l16] = (bf16_t)p1[r];
            }
            bf16x8 pa = *(const bf16x8*)(pw + l16 * PSTR + lg * 8);
            // PV: O[16][64] += P[16][32] * V[32][64]
#pragma unroll
            for (int n = 0; n < 4; n++) {
                bf16x8 vb = *(const bf16x8*)(vt + (n * 16 + l16) * VTS + lg * 8);
                o[n] = mfma16(pa, vb, o[n]);
            }
        }
        __syncthreads();   // protect vt before next stage
    }

    // epilogue: O / l  (fully-masked rows -> 0)
    float* op = Out + bh_off;
#pragma unroll
    for (int r = 0; r < 4; r++) {
        float inv  = (lrow[r] > 0.f) ? (1.f / lrow[r]) : 0.f;
        int   rowg = q0 + lg * 4 + r;
#pragma unroll
        for (int n = 0; n < 4; n++)
            op[(size_t)rowg * Dc + n * 16 + l16] = o[n][r] * inv;
    }
}

extern "C" void kernel_launch(void* const* d_in, const int* in_sizes, int n_in,
                              void* d_out, int out_size, void* d_ws, size_t ws_size,
                              hipStream_t stream) {
    const float* Q    = (const float*)d_in[0];
    const float* K    = (const float*)d_in[1];
    const float* V    = (const float*)d_in[2];
    const float* bias = (const float*)d_in[3];
    const int*   mask = (const int*)d_in[4];
    float* out = (float*)d_out;

    char* ws = (char*)d_ws;
    bf16_t* kh = (bf16_t*)ws;                                  // 8 MiB
    bf16_t* kl = (bf16_t*)(ws + QKV_ELEMS * 2);                // 8 MiB
    unsigned char* bm = (unsigned char*)(ws + QKV_ELEMS * 4);  // 64 KiB

    k_convert  <<<(int)(QKV_ELEMS / (256 * 8)), 256, 0, stream>>>(K, kh, kl);
    k_blockmask<<<Hc * NB,                      256, 0, stream>>>(mask, bias, bm);
    k_attn     <<<Bc * Hc * (Sc / 64),          256, 0, stream>>>(Q, V, kh, kl, bm, out);
}

// Round 2
// 207.936 us; speedup vs baseline: 1.6034x; 1.6034x over previous
//
#include <hip/hip_runtime.h>
#include <hip/hip_bf16.h>

// TritonDynamicAttention: blocksparse causal attention, B=2,H=16,S=2048,D=64, BLOCK=32.
// R1: barrier-free flash attention. V pre-transposed to bf16 V^T so PV B-frags are
// direct global loads; 1 wave/WG; heavy-first swizzle; K-frag double buffering.

typedef __bf16 bf16_t;
typedef bf16_t bf16x8 __attribute__((ext_vector_type(8)));
typedef float  f32x4  __attribute__((ext_vector_type(4)));
typedef int    i32x4  __attribute__((ext_vector_type(4)));

constexpr int Bc = 2, Hc = 16, Sc = 2048, Dc = 64;
constexpr int NB = Sc / 32;                              // 64 mask blocks per side
constexpr size_t QKV_ELEMS = (size_t)Bc * Hc * Sc * Dc;  // 4194304
constexpr int PSTR = 40;                                 // LDS P row stride (elems)

__device__ inline f32x4 mfma16(bf16x8 a, bf16x8 b, f32x4 c) {
    return __builtin_amdgcn_mfma_f32_16x16x32_bf16(a, b, c, 0, 0, 0);
}

// ---------- kernel 1: K fp32 -> (Kh, Kl) bf16 split ----------
__global__ __launch_bounds__(256) void k_convert(const float* __restrict__ k,
                                                 bf16_t* __restrict__ kh,
                                                 bf16_t* __restrict__ kl) {
    size_t i = ((size_t)blockIdx.x * 256 + threadIdx.x) * 8;
    f32x4 a = *(const f32x4*)(k + i);
    f32x4 b = *(const f32x4*)(k + i + 4);
    float xs[8] = {a[0], a[1], a[2], a[3], b[0], b[1], b[2], b[3]};
    bf16x8 h, l;
#pragma unroll
    for (int j = 0; j < 8; j++) {
        bf16_t hh = (bf16_t)xs[j];
        h[j] = hh;
        l[j] = (bf16_t)(xs[j] - (float)hh);
    }
    *(bf16x8*)(kh + i) = h;
    *(bf16x8*)(kl + i) = l;
}

// ---------- kernel 1b: V fp32 [bh][s][d] -> bf16 V^T [bh][d][s] ----------
__global__ __launch_bounds__(256) void k_vtrans(const float* __restrict__ v,
                                                bf16_t* __restrict__ vt) {
    __shared__ bf16_t tile[64 * 66];
    const int bh = blockIdx.x >> 5;     // 32 bh
    const int st = blockIdx.x & 31;     // 32 s-tiles of 64
    const int t  = threadIdx.x;
    {
        int sr = t >> 2, dseg = (t & 3) * 16;
        const float* vr = v + ((size_t)bh * Sc + (size_t)st * 64 + sr) * Dc + dseg;
#pragma unroll
        for (int c = 0; c < 4; c++) {
            f32x4 a = *(const f32x4*)(vr + c * 4);
#pragma unroll
            for (int j = 0; j < 4; j++) tile[sr * 66 + dseg + c * 4 + j] = (bf16_t)a[j];
        }
    }
    __syncthreads();
    {
        int dr = t >> 2, sseg = (t & 3) * 16;
        bf16x8 h0, h1;
#pragma unroll
        for (int j = 0; j < 8; j++) h0[j] = tile[(sseg + j) * 66 + dr];
#pragma unroll
        for (int j = 0; j < 8; j++) h1[j] = tile[(sseg + 8 + j) * 66 + dr];
        bf16_t* outp = vt + ((size_t)bh * Dc + dr) * Sc + (size_t)st * 64 + sseg;
        *(bf16x8*)outp = h0;
        *(bf16x8*)(outp + 8) = h1;
    }
}

// ---------- kernel 2: block mask ----------
__global__ __launch_bounds__(256) void k_blockmask(const int* __restrict__ mask,
                                                   const float* __restrict__ bias,
                                                   unsigned char* __restrict__ bm) {
    int h  = blockIdx.x / NB;
    int br = blockIdx.x % NB;
    float bv = bias[h];
    unsigned char* outp = bm + ((size_t)h * NB + br) * NB;
    int t = threadIdx.x;
    if (bv > 0.f) {
        if (t < NB) outp[t] = 1;
        return;
    }
    int bc0 = t >> 3;
    int bc1 = 32 + bc0;
    const int* base = mask + ((size_t)h * Sc + (size_t)br * 32) * (size_t)Sc;
    int acc0 = 0, acc1 = 0;
    bool d0 = (bc0 <= br), d1 = (bc1 <= br);
    if (d0) {
        const int* p = base + 4 * t;
#pragma unroll 8
        for (int r = 0; r < 32; r++) {
            i32x4 vv = *(const i32x4*)(p + (size_t)r * Sc);
            acc0 += vv[0] + vv[1] + vv[2] + vv[3];
        }
    }
    if (d1) {
        const int* p = base + 1024 + 4 * t;
#pragma unroll 8
        for (int r = 0; r < 32; r++) {
            i32x4 vv = *(const i32x4*)(p + (size_t)r * Sc);
            acc1 += vv[0] + vv[1] + vv[2] + vv[3];
        }
    }
#pragma unroll
    for (int off = 1; off < 8; off <<= 1) {
        acc0 += __shfl_xor(acc0, off);
        acc1 += __shfl_xor(acc1, off);
    }
    if ((t & 7) == 0) {
        if (d0) outp[bc0] = ((float)acc0 + bv > 0.f) ? 1 : 0;
        if (d1) outp[bc1] = ((float)acc1 + bv > 0.f) ? 1 : 0;
    }
}

// ---------- kernel 3: barrier-free flash blocksparse causal attention ----------
// Grid: 4096 WGs of 64 (1 wave). Wave owns 16 q-rows; heavy tiles first.
#define KLOAD(KH_, KL_, kb_) do {                                              \
    _Pragma("unroll")                                                          \
    for (int t_ = 0; t_ < 2; t_++) {                                           \
        size_t kro_ = (size_t)(((kb_) * 32 + t_ * 16 + l16) * Dc) + lg * 8;    \
        _Pragma("unroll")                                                      \
        for (int ks_ = 0; ks_ < 2; ks_++) {                                    \
            KH_[t_][ks_] = *(const bf16x8*)(khp + kro_ + ks_ * 32);            \
            KL_[t_][ks_] = *(const bf16x8*)(klp + kro_ + ks_ * 32);            \
        }                                                                      \
    }                                                                          \
} while (0)

#define STEP(KH_, KL_, kb_) do {                                               \
    if ((actmask >> (kb_)) & 1ull) {                                           \
        bf16x8 vb_[4];                                                         \
        _Pragma("unroll")                                                      \
        for (int n_ = 0; n_ < 4; n_++)                                         \
            vb_[n_] = *(const bf16x8*)(vtp + (size_t)(n_ * 16 + l16) * Sc +    \
                                       (kb_) * 32 + lg * 8);                   \
        f32x4 s0, s1;                                                          \
        s0[0]=s0[1]=s0[2]=s0[3]=0.f; s1[0]=s1[1]=s1[2]=s1[3]=0.f;              \
        _Pragma("unroll")                                                      \
        for (int ks_ = 0; ks_ < 2; ks_++) {                                    \
            s0 = mfma16(qh[ks_], KH_[0][ks_], s0);                             \
            s1 = mfma16(qh[ks_], KH_[1][ks_], s1);                             \
            s0 = mfma16(qh[ks_], KL_[0][ks_], s0);                             \
            s1 = mfma16(qh[ks_], KL_[1][ks_], s1);                             \
            s0 = mfma16(ql[ks_], KH_[0][ks_], s0);                             \
            s1 = mfma16(ql[ks_], KH_[1][ks_], s1);                             \
        }                                                                      \
        if ((kb_) == brow) {                                                   \
            _Pragma("unroll")                                                  \
            for (int r_ = 0; r_ < 4; r_++) {                                   \
                int rowg_ = q0 + lg * 4 + r_;                                  \
                int c0_   = (kb_) * 32 + l16;                                  \
                if (c0_ > rowg_)      s0[r_] = -1e30f;                         \
                if (c0_ + 16 > rowg_) s1[r_] = -1e30f;                         \
            }                                                                  \
        }                                                                      \
        _Pragma("unroll")                                                      \
        for (int r_ = 0; r_ < 4; r_++) {                                       \
            float mx_ = fmaxf(s0[r_], s1[r_]);                                 \
            _Pragma("unroll")                                                  \
            for (int off_ = 1; off_ < 16; off_ <<= 1)                          \
                mx_ = fmaxf(mx_, __shfl_xor(mx_, off_));                       \
            float mn_ = fmaxf(mrow[r_], mx_);                                  \
            float al_ = __expf(mrow[r_] - mn_);                                \
            mrow[r_] = mn_;                                                    \
            float e0_ = __expf(s0[r_] - mn_), e1_ = __expf(s1[r_] - mn_);      \
            lrow[r_] = lrow[r_] * al_ + e0_ + e1_;                             \
            _Pragma("unroll")                                                  \
            for (int n_ = 0; n_ < 4; n_++) o[n_][r_] *= al_;                   \
            pl[(lg * 4 + r_) * PSTR + l16]      = (bf16_t)e0_;                 \
            pl[(lg * 4 + r_) * PSTR + 16 + l16] = (bf16_t)e1_;                 \
        }                                                                      \
        bf16x8 pa_ = *(const bf16x8*)(pl + l16 * PSTR + lg * 8);               \
        _Pragma("unroll")                                                      \
        for (int n_ = 0; n_ < 4; n_++) o[n_] = mfma16(pa_, vb_[n_], o[n_]);    \
    }                                                                          \
} while (0)

__global__ __launch_bounds__(64) void k_attn(const float* __restrict__ Q,
                                             const bf16_t* __restrict__ KH,
                                             const bf16_t* __restrict__ KL,
                                             const bf16_t* __restrict__ VT,
                                             const unsigned char* __restrict__ BM,
                                             float* __restrict__ Out) {
    __shared__ bf16_t pl[16 * PSTR];

    const int qi   = 127 - (blockIdx.x >> 5);  // heavy tiles dispatch first
    const int bh   = blockIdx.x & 31;
    const int h    = bh & (Hc - 1);
    const int lane = threadIdx.x;
    const int l16  = lane & 15, lg = lane >> 4;

    const size_t bh_off = (size_t)bh * Sc * Dc;
    const float*  q_ptr = Q  + bh_off;
    const bf16_t* khp   = KH + bh_off;
    const bf16_t* klp   = KL + bh_off;
    const bf16_t* vtp   = VT + bh_off;

    const int q0   = qi * 16;
    const int brow = q0 >> 5;
    const unsigned char* bmrow = BM + ((size_t)h * NB + brow) * NB;
    const unsigned long long actmask = __ballot(bmrow[lane] != 0);

    // Q fragments: lane holds Q[q0+l16][ks*32 + lg*8 + j], hi/lo split
    bf16x8 qh[2], ql[2];
    {
        const float* qr = q_ptr + (size_t)(q0 + l16) * Dc + lg * 8;
#pragma unroll
        for (int ks = 0; ks < 2; ks++) {
            f32x4 a = *(const f32x4*)(qr + ks * 32);
            f32x4 b = *(const f32x4*)(qr + ks * 32 + 4);
            float xs[8] = {a[0], a[1], a[2], a[3], b[0], b[1], b[2], b[3]};
#pragma unroll
            for (int j = 0; j < 8; j++) {
                bf16_t hh = (bf16_t)xs[j];
                qh[ks][j] = hh;
                ql[ks][j] = (bf16_t)(xs[j] - (float)hh);
            }
        }
    }

    f32x4 o[4];
    float mrow[4], lrow[4];
#pragma unroll
    for (int n = 0; n < 4; n++) { o[n][0]=0.f; o[n][1]=0.f; o[n][2]=0.f; o[n][3]=0.f; }
#pragma unroll
    for (int r = 0; r < 4; r++) { mrow[r] = -INFINITY; lrow[r] = 0.f; }

    const int kbmax = brow;
    bf16x8 kha[2][2], kla[2][2], khb[2][2], klb[2][2];
    KLOAD(kha, kla, 0);
    int kb = 0;
    while (true) {
        if (kb + 1 <= kbmax) KLOAD(khb, klb, kb + 1);
        STEP(kha, kla, kb);
        if (kb + 1 > kbmax) break;
        if (kb + 2 <= kbmax) KLOAD(kha, kla, kb + 2);
        STEP(khb, klb, kb + 1);
        if (kb + 2 > kbmax) break;
        kb += 2;
    }

    // epilogue: reduce l across the 16-lane group, normalize, store
    float* op = Out + bh_off;
#pragma unroll
    for (int r = 0; r < 4; r++) {
#pragma unroll
        for (int off = 1; off < 16; off <<= 1) lrow[r] += __shfl_xor(lrow[r], off);
        float inv  = (lrow[r] > 0.f) ? (1.f / lrow[r]) : 0.f;
        int   rowg = q0 + lg * 4 + r;
#pragma unroll
        for (int n = 0; n < 4; n++)
            op[(size_t)rowg * Dc + n * 16 + l16] = o[n][r] * inv;
    }
}

extern "C" void kernel_launch(void* const* d_in, const int* in_sizes, int n_in,
                              void* d_out, int out_size, void* d_ws, size_t ws_size,
                              hipStream_t stream) {
    const float* Q    = (const float*)d_in[0];
    const float* K    = (const float*)d_in[1];
    const float* V    = (const float*)d_in[2];
    const float* bias = (const float*)d_in[3];
    const int*   mask = (const int*)d_in[4];
    float* out = (float*)d_out;

    char* ws = (char*)d_ws;
    bf16_t* kh = (bf16_t*)ws;                                  // 8 MiB
    bf16_t* kl = (bf16_t*)(ws + QKV_ELEMS * 2);                // 8 MiB
    bf16_t* vt = (bf16_t*)(ws + QKV_ELEMS * 4);                // 8 MiB
    unsigned char* bm = (unsigned char*)(ws + QKV_ELEMS * 6);  // 64 KiB

    k_convert  <<<(int)(QKV_ELEMS / (256 * 8)), 256, 0, stream>>>(K, kh, kl);
    k_vtrans   <<<Bc * Hc * (Sc / 64),          256, 0, stream>>>(V, vt);
    k_blockmask<<<Hc * NB,                      256, 0, stream>>>(mask, bias, bm);
    k_attn     <<<Bc * Hc * (Sc / 16),          64,  0, stream>>>(Q, kh, kl, vt, bm, out);
}

// Round 3
// 141.079 us; speedup vs baseline: 2.3633x; 1.4739x over previous
//
#include <hip/hip_runtime.h>
#include <hip/hip_bf16.h>

// TritonDynamicAttention: blocksparse causal attention, B=2,H=16,S=2048,D=64, BLOCK=32.
// R2: 32x32 MFMA with swapped operands (S^T = K·Q^T layout). Softmax column lives in
// one lane (16 regs + lane^32 half) -> in-register reduce, P never touches LDS.
// PV computed as O^T = V^T·P^T. Barrier-free, LDS-free attention kernel.

typedef __bf16 bf16_t;
typedef bf16_t bf16x8 __attribute__((ext_vector_type(8)));
typedef float  f32x4  __attribute__((ext_vector_type(4)));
typedef float  f32x16 __attribute__((ext_vector_type(16)));
typedef int    i32x4  __attribute__((ext_vector_type(4)));
typedef unsigned int u32x4 __attribute__((ext_vector_type(4)));

constexpr int Bc = 2, Hc = 16, Sc = 2048, Dc = 64;
constexpr int NB = Sc / 32;                              // 64 mask blocks per side
constexpr size_t QKV_ELEMS = (size_t)Bc * Hc * Sc * Dc;  // 4194304

__device__ inline f32x16 mfma32(bf16x8 a, bf16x8 b, f32x16 c) {
    return __builtin_amdgcn_mfma_f32_32x32x16_bf16(a, b, c, 0, 0, 0);
}

union UB { u32x4 u; bf16x8 v; };
union HB { bf16_t h; unsigned short s; };

__device__ inline unsigned int pack_bf16(float lo, float hi) {
    HB a, b; a.h = (bf16_t)lo; b.h = (bf16_t)hi;
    return (unsigned int)a.s | ((unsigned int)b.s << 16);
}

// ---------- kernel 1: K fp32 -> (Kh, Kl) bf16 split ----------
__global__ __launch_bounds__(256) void k_convert(const float* __restrict__ k,
                                                 bf16_t* __restrict__ kh,
                                                 bf16_t* __restrict__ kl) {
    size_t i = ((size_t)blockIdx.x * 256 + threadIdx.x) * 8;
    f32x4 a = *(const f32x4*)(k + i);
    f32x4 b = *(const f32x4*)(k + i + 4);
    float xs[8] = {a[0], a[1], a[2], a[3], b[0], b[1], b[2], b[3]};
    bf16x8 h, l;
#pragma unroll
    for (int j = 0; j < 8; j++) {
        bf16_t hh = (bf16_t)xs[j];
        h[j] = hh;
        l[j] = (bf16_t)(xs[j] - (float)hh);
    }
    *(bf16x8*)(kh + i) = h;
    *(bf16x8*)(kl + i) = l;
}

// ---------- kernel 1b: V fp32 [bh][s][d] -> bf16 V^T [bh][d][s] ----------
__global__ __launch_bounds__(256) void k_vtrans(const float* __restrict__ v,
                                                bf16_t* __restrict__ vt) {
    __shared__ bf16_t tile[64 * 66];
    const int bh = blockIdx.x >> 5;
    const int st = blockIdx.x & 31;
    const int t  = threadIdx.x;
    {
        int sr = t >> 2, dseg = (t & 3) * 16;
        const float* vr = v + ((size_t)bh * Sc + (size_t)st * 64 + sr) * Dc + dseg;
#pragma unroll
        for (int c = 0; c < 4; c++) {
            f32x4 a = *(const f32x4*)(vr + c * 4);
#pragma unroll
            for (int j = 0; j < 4; j++) tile[sr * 66 + dseg + c * 4 + j] = (bf16_t)a[j];
        }
    }
    __syncthreads();
    {
        int dr = t >> 2, sseg = (t & 3) * 16;
        bf16x8 h0, h1;
#pragma unroll
        for (int j = 0; j < 8; j++) h0[j] = tile[(sseg + j) * 66 + dr];
#pragma unroll
        for (int j = 0; j < 8; j++) h1[j] = tile[(sseg + 8 + j) * 66 + dr];
        bf16_t* outp = vt + ((size_t)bh * Dc + dr) * Sc + (size_t)st * 64 + sseg;
        *(bf16x8*)outp = h0;
        *(bf16x8*)(outp + 8) = h1;
    }
}

// ---------- kernel 2: block mask ----------
__global__ __launch_bounds__(256) void k_blockmask(const int* __restrict__ mask,
                                                   const float* __restrict__ bias,
                                                   unsigned char* __restrict__ bm) {
    int h  = blockIdx.x / NB;
    int br = blockIdx.x % NB;
    float bv = bias[h];
    unsigned char* outp = bm + ((size_t)h * NB + br) * NB;
    int t = threadIdx.x;
    if (bv > 0.f) {
        if (t < NB) outp[t] = 1;
        return;
    }
    int bc0 = t >> 3;
    int bc1 = 32 + bc0;
    const int* base = mask + ((size_t)h * Sc + (size_t)br * 32) * (size_t)Sc;
    int acc0 = 0, acc1 = 0;
    bool d0 = (bc0 <= br), d1 = (bc1 <= br);
    if (d0) {
        const int* p = base + 4 * t;
#pragma unroll 8
        for (int r = 0; r < 32; r++) {
            i32x4 vv = *(const i32x4*)(p + (size_t)r * Sc);
            acc0 += vv[0] + vv[1] + vv[2] + vv[3];
        }
    }
    if (d1) {
        const int* p = base + 1024 + 4 * t;
#pragma unroll 8
        for (int r = 0; r < 32; r++) {
            i32x4 vv = *(const i32x4*)(p + (size_t)r * Sc);
            acc1 += vv[0] + vv[1] + vv[2] + vv[3];
        }
    }
#pragma unroll
    for (int off = 1; off < 8; off <<= 1) {
        acc0 += __shfl_xor(acc0, off);
        acc1 += __shfl_xor(acc1, off);
    }
    if ((t & 7) == 0) {
        if (d0) outp[bc0] = ((float)acc0 + bv > 0.f) ? 1 : 0;
        if (d1) outp[bc1] = ((float)acc1 + bv > 0.f) ? 1 : 0;
    }
}

// ---------- kernel 3: flash blocksparse causal attention, 32x32 swapped ----------
// Grid: 2048 WGs of 64 (1 wave). Wave owns 32 q-rows (one mask block-row).
// S^T[kv][q]: q = lane&31 (col), kv = (r&3)+8*(r>>2)+4*hi (row), r = reg 0..15.
#define KLOAD(KH_, KL_, kb_) do {                                              \
    _Pragma("unroll")                                                          \
    for (int kc_ = 0; kc_ < 4; kc_++) {                                        \
        size_t o_ = (size_t)(((kb_) * 32 + l31) * Dc) + kc_ * 16 + hi * 8;     \
        KH_[kc_] = *(const bf16x8*)(khp + o_);                                 \
        KL_[kc_] = *(const bf16x8*)(klp + o_);                                 \
    }                                                                          \
} while (0)

#define STEP(KH_, KL_, kb_) do {                                               \
    if ((actmask >> (kb_)) & 1ull) {                                           \
        bf16x8 va_[2][2];                                                      \
        _Pragma("unroll")                                                      \
        for (int t_ = 0; t_ < 2; t_++)                                         \
            _Pragma("unroll")                                                  \
            for (int c_ = 0; c_ < 2; c_++)                                     \
                va_[t_][c_] = *(const bf16x8*)(vtp + (size_t)(t_ * 32 + l31) * Sc \
                                               + (kb_) * 32 + c_ * 16 + hi * 8);  \
        f32x16 st;                                                             \
        _Pragma("unroll")                                                      \
        for (int r_ = 0; r_ < 16; r_++) st[r_] = 0.f;                          \
        _Pragma("unroll")                                                      \
        for (int kc_ = 0; kc_ < 4; kc_++) {                                    \
            st = mfma32(KH_[kc_], qh[kc_], st);                                \
            st = mfma32(KH_[kc_], ql[kc_], st);                                \
            st = mfma32(KL_[kc_], qh[kc_], st);                                \
        }                                                                      \
        if ((kb_) == brow) {                                                   \
            _Pragma("unroll")                                                  \
            for (int r_ = 0; r_ < 16; r_++) {                                  \
                int kvl_ = (r_ & 3) + 8 * (r_ >> 2) + 4 * hi;                  \
                if (kvl_ > l31) st[r_] = -1e30f;                               \
            }                                                                  \
        }                                                                      \
        float mx_;                                                             \
        {                                                                      \
            float t0 = fmaxf(st[0], st[1]),   t1 = fmaxf(st[2], st[3]);        \
            float t2 = fmaxf(st[4], st[5]),   t3 = fmaxf(st[6], st[7]);        \
            float t4 = fmaxf(st[8], st[9]),   t5 = fmaxf(st[10], st[11]);      \
            float t6 = fmaxf(st[12], st[13]), t7 = fmaxf(st[14], st[15]);      \
            t0 = fmaxf(t0, t1); t2 = fmaxf(t2, t3);                            \
            t4 = fmaxf(t4, t5); t6 = fmaxf(t6, t7);                            \
            mx_ = fmaxf(fmaxf(t0, t2), fmaxf(t4, t6));                         \
        }                                                                      \
        mx_ = fmaxf(mx_, __shfl_xor(mx_, 32));                                 \
        float mn_ = fmaxf(mrow, mx_);                                          \
        float al_ = __expf(mrow - mn_);                                        \
        mrow = mn_;                                                            \
        float p_[16];                                                          \
        _Pragma("unroll")                                                      \
        for (int r_ = 0; r_ < 16; r_++) p_[r_] = __expf(st[r_] - mn_);         \
        {                                                                      \
            float s0 = (p_[0] + p_[1]) + (p_[2] + p_[3]);                      \
            float s1 = (p_[4] + p_[5]) + (p_[6] + p_[7]);                      \
            float s2 = (p_[8] + p_[9]) + (p_[10] + p_[11]);                    \
            float s3 = (p_[12] + p_[13]) + (p_[14] + p_[15]);                  \
            lrow = lrow * al_ + ((s0 + s1) + (s2 + s3));                       \
        }                                                                      \
        ot0 *= al_; ot1 *= al_;                                                \
        unsigned int pb_[8], qb_[8];                                           \
        _Pragma("unroll")                                                      \
        for (int i_ = 0; i_ < 8; i_++)                                         \
            pb_[i_] = pack_bf16(p_[2 * i_], p_[2 * i_ + 1]);                   \
        _Pragma("unroll")                                                      \
        for (int i_ = 0; i_ < 8; i_++)                                         \
            qb_[i_] = (unsigned int)__shfl_xor((int)pb_[i_], 32);              \
        UB b0_, b1_;                                                           \
        b0_.u[0] = hi ? qb_[2] : pb_[0]; b0_.u[1] = hi ? qb_[3] : pb_[1];      \
        b0_.u[2] = hi ? pb_[2] : qb_[0]; b0_.u[3] = hi ? pb_[3] : qb_[1];      \
        b1_.u[0] = hi ? qb_[6] : pb_[4]; b1_.u[1] = hi ? qb_[7] : pb_[5];      \
        b1_.u[2] = hi ? pb_[6] : qb_[4]; b1_.u[3] = hi ? pb_[7] : qb_[5];      \
        ot0 = mfma32(va_[0][0], b0_.v, ot0);                                   \
        ot0 = mfma32(va_[0][1], b1_.v, ot0);                                   \
        ot1 = mfma32(va_[1][0], b0_.v, ot1);                                   \
        ot1 = mfma32(va_[1][1], b1_.v, ot1);                                   \
    }                                                                          \
} while (0)

__global__ __launch_bounds__(64) void k_attn(const float* __restrict__ Q,
                                             const bf16_t* __restrict__ KH,
                                             const bf16_t* __restrict__ KL,
                                             const bf16_t* __restrict__ VT,
                                             const unsigned char* __restrict__ BM,
                                             float* __restrict__ Out) {
    const int qi   = 63 - (int)(blockIdx.x >> 5);   // heavy block-rows dispatch first
    const int bh   = blockIdx.x & 31;
    const int h    = bh & (Hc - 1);
    const int lane = threadIdx.x;
    const int l31  = lane & 31, hi = lane >> 5;

    const size_t bh_off = (size_t)bh * Sc * Dc;
    const float*  q_ptr = Q  + bh_off;
    const bf16_t* khp   = KH + bh_off;
    const bf16_t* klp   = KL + bh_off;
    const bf16_t* vtp   = VT + bh_off;

    const int q0   = qi * 32;
    const int brow = qi;
    const unsigned char* bmrow = BM + ((size_t)h * NB + brow) * NB;
    const unsigned long long actmask = __ballot(bmrow[lane] != 0);

    // Q fragments (B-operand of S^T): lane holds Q[q0+l31][kc*16 + hi*8 + j], hi/lo split
    bf16x8 qh[4], ql[4];
    {
        const float* qr = q_ptr + (size_t)(q0 + l31) * Dc + hi * 8;
#pragma unroll
        for (int kc = 0; kc < 4; kc++) {
            f32x4 a = *(const f32x4*)(qr + kc * 16);
            f32x4 b = *(const f32x4*)(qr + kc * 16 + 4);
            float xs[8] = {a[0], a[1], a[2], a[3], b[0], b[1], b[2], b[3]};
#pragma unroll
            for (int j = 0; j < 8; j++) {
                bf16_t hh = (bf16_t)xs[j];
                qh[kc][j] = hh;
                ql[kc][j] = (bf16_t)(xs[j] - (float)hh);
            }
        }
    }

    f32x16 ot0, ot1;
#pragma unroll
    for (int r = 0; r < 16; r++) { ot0[r] = 0.f; ot1[r] = 0.f; }
    float mrow = -INFINITY, lrow = 0.f;

    bf16x8 kha[4], kla[4], khb[4], klb[4];
    KLOAD(kha, kla, 0);
    int kb = 0;
    while (true) {
        if (kb + 1 <= brow) KLOAD(khb, klb, kb + 1);
        STEP(kha, kla, kb);
        if (kb + 1 > brow) break;
        if (kb + 2 <= brow) KLOAD(kha, kla, kb + 2);
        STEP(khb, klb, kb + 1);
        if (kb + 2 > brow) break;
        kb += 2;
    }

    // epilogue: combine the two lane-halves' l partials, normalize, store O^T -> Out
    lrow += __shfl_xor(lrow, 32);
    float inv = (lrow > 0.f) ? (1.f / lrow) : 0.f;
    float* op = Out + bh_off + (size_t)(q0 + l31) * Dc;
#pragma unroll
    for (int g = 0; g < 4; g++) {
        f32x4 w0, w1;
#pragma unroll
        for (int j = 0; j < 4; j++) { w0[j] = ot0[g * 4 + j] * inv; w1[j] = ot1[g * 4 + j] * inv; }
        *(f32x4*)(op + g * 8 + hi * 4)      = w0;
        *(f32x4*)(op + 32 + g * 8 + hi * 4) = w1;
    }
}

extern "C" void kernel_launch(void* const* d_in, const int* in_sizes, int n_in,
                              void* d_out, int out_size, void* d_ws, size_t ws_size,
                              hipStream_t stream) {
    const float* Q    = (const float*)d_in[0];
    const float* K    = (const float*)d_in[1];
    const float* V    = (const float*)d_in[2];
    const float* bias = (const float*)d_in[3];
    const int*   mask = (const int*)d_in[4];
    float* out = (float*)d_out;

    char* ws = (char*)d_ws;
    bf16_t* kh = (bf16_t*)ws;                                  // 8 MiB
    bf16_t* kl = (bf16_t*)(ws + QKV_ELEMS * 2);                // 8 MiB
    bf16_t* vt = (bf16_t*)(ws + QKV_ELEMS * 4);                // 8 MiB
    unsigned char* bm = (unsigned char*)(ws + QKV_ELEMS * 6);  // 64 KiB

    k_convert  <<<(int)(QKV_ELEMS / (256 * 8)), 256, 0, stream>>>(K, kh, kl);
    k_vtrans   <<<Bc * Hc * (Sc / 64),          256, 0, stream>>>(V, vt);
    k_blockmask<<<Hc * NB,                      256, 0, stream>>>(mask, bias, bm);
    k_attn     <<<Bc * Hc * (Sc / 32),          64,  0, stream>>>(Q, kh, kl, vt, bm, out);
}

// Round 5
// 117.525 us; speedup vs baseline: 2.8369x; 1.2004x over previous
//
#include <hip/hip_runtime.h>
#include <hip/hip_bf16.h>

// TritonDynamicAttention: blocksparse causal attention, B=2,H=16,S=2048,D=64, BLOCK=32.
// R4: fp16 carrier (2^-11 rounding) -> single-term QK (4 MFMAs) + fp16 PV, no hi/lo
// split needed. Keeps R3 structure: 2-wave kv-parity split + exact LDS merge,
// __launch_bounds__(128,4), fused prep kernel, heavy-first dispatch order.

typedef _Float16 f16_t;
typedef f16_t  f16x8  __attribute__((ext_vector_type(8)));
typedef float  f32x4  __attribute__((ext_vector_type(4)));
typedef float  f32x16 __attribute__((ext_vector_type(16)));
typedef int    i32x4  __attribute__((ext_vector_type(4)));
typedef unsigned int u32x4 __attribute__((ext_vector_type(4)));

constexpr int Bc = 2, Hc = 16, Sc = 2048, Dc = 64;
constexpr int NB = Sc / 32;                              // 64 mask blocks per side
constexpr size_t QKV_ELEMS = (size_t)Bc * Hc * Sc * Dc;  // 4194304

__device__ inline f32x16 mfma32(f16x8 a, f16x8 b, f32x16 c) {
    return __builtin_amdgcn_mfma_f32_32x32x16_f16(a, b, c, 0, 0, 0);
}

union UB { u32x4 u; f16x8 v; };
union HB { f16_t h; unsigned short s; };

__device__ inline unsigned int pack_f16(float lo, float hi) {
    HB a, b; a.h = (f16_t)lo; b.h = (f16_t)hi;
    return (unsigned int)a.s | ((unsigned int)b.s << 16);
}

// ---------- fused prep: [0,2048) K->f16 | [2048,3072) V^T f16 | [3072,4096) blockmask --
__global__ __launch_bounds__(256) void k_prep(const float* __restrict__ K,
                                              const float* __restrict__ V,
                                              const int* __restrict__ mask,
                                              const float* __restrict__ bias,
                                              f16_t* __restrict__ kh,
                                              f16_t* __restrict__ vt,
                                              unsigned char* __restrict__ bm) {
    const int bid = blockIdx.x;
    const int t   = threadIdx.x;
    if (bid < 2048) {
        size_t i = ((size_t)bid * 256 + t) * 8;
        f32x4 a = *(const f32x4*)(K + i);
        f32x4 b = *(const f32x4*)(K + i + 4);
        float xs[8] = {a[0], a[1], a[2], a[3], b[0], b[1], b[2], b[3]};
        f16x8 h;
#pragma unroll
        for (int j = 0; j < 8; j++) h[j] = (f16_t)xs[j];
        *(f16x8*)(kh + i) = h;
    } else if (bid < 3072) {
        __shared__ f16_t tile[64 * 66];
        const int b2 = bid - 2048;
        const int bh = b2 >> 5;
        const int st = b2 & 31;
        {
            int sr = t >> 2, dseg = (t & 3) * 16;
            const float* vr = V + ((size_t)bh * Sc + (size_t)st * 64 + sr) * Dc + dseg;
#pragma unroll
            for (int c = 0; c < 4; c++) {
                f32x4 a = *(const f32x4*)(vr + c * 4);
#pragma unroll
                for (int j = 0; j < 4; j++) tile[sr * 66 + dseg + c * 4 + j] = (f16_t)a[j];
            }
        }
        __syncthreads();
        {
            int dr = t >> 2, sseg = (t & 3) * 16;
            f16x8 h0, h1;
#pragma unroll
            for (int j = 0; j < 8; j++) h0[j] = tile[(sseg + j) * 66 + dr];
#pragma unroll
            for (int j = 0; j < 8; j++) h1[j] = tile[(sseg + 8 + j) * 66 + dr];
            f16_t* outp = vt + ((size_t)bh * Dc + dr) * Sc + (size_t)st * 64 + sseg;
            *(f16x8*)outp = h0;
            *(f16x8*)(outp + 8) = h1;
        }
    } else {
        const int b3 = bid - 3072;
        const int h  = b3 >> 6;
        const int br = b3 & 63;
        float bv = bias[h];
        unsigned char* outp = bm + ((size_t)h * NB + br) * NB;
        if (bv > 0.f) {
            if (t < NB) outp[t] = 1;
            return;
        }
        int bc0 = t >> 3;
        int bc1 = 32 + bc0;
        const int* base = mask + ((size_t)h * Sc + (size_t)br * 32) * (size_t)Sc;
        int acc0 = 0, acc1 = 0;
        bool d0 = (bc0 <= br), d1 = (bc1 <= br);
        if (d0) {
            const int* p = base + 4 * t;
#pragma unroll 8
            for (int r = 0; r < 32; r++) {
                i32x4 vv = *(const i32x4*)(p + (size_t)r * Sc);
                acc0 += vv[0] + vv[1] + vv[2] + vv[3];
            }
        }
        if (d1) {
            const int* p = base + 1024 + 4 * t;
#pragma unroll 8
            for (int r = 0; r < 32; r++) {
                i32x4 vv = *(const i32x4*)(p + (size_t)r * Sc);
                acc1 += vv[0] + vv[1] + vv[2] + vv[3];
            }
        }
#pragma unroll
        for (int off = 1; off < 8; off <<= 1) {
            acc0 += __shfl_xor(acc0, off);
            acc1 += __shfl_xor(acc1, off);
        }
        if ((t & 7) == 0) {
            if (d0) outp[bc0] = ((float)acc0 + bv > 0.f) ? 1 : 0;
            if (d1) outp[bc1] = ((float)acc1 + bv > 0.f) ? 1 : 0;
        }
    }
}

// ---------- flash blocksparse causal attention, 32x32 swapped, fp16, parity split ------
// Grid: 2048 WGs of 128 (2 waves). WG owns one (bh, qi block-row); wave w takes
// kb == w (mod 2); partials merged via LDS (exact flash-decode merge).
// S^T[kv][q]: q = lane&31, kv = (r&3)+8*(r>>2)+4*hi, r = reg 0..15.
#define KLOAD(KB_, kb_) do {                                                   \
    _Pragma("unroll")                                                          \
    for (int kc_ = 0; kc_ < 4; kc_++)                                          \
        KB_[kc_] = *(const f16x8*)(khp + (size_t)(((kb_) * 32 + l31) * Dc)     \
                                   + kc_ * 16 + hi * 8);                       \
} while (0)

#define STEP(KB_, kb_) do {                                                    \
    if ((actmask >> (kb_)) & 1ull) {                                           \
        f16x8 va_[2][2];                                                       \
        _Pragma("unroll")                                                      \
        for (int t_ = 0; t_ < 2; t_++)                                         \
            _Pragma("unroll")                                                  \
            for (int c_ = 0; c_ < 2; c_++)                                     \
                va_[t_][c_] = *(const f16x8*)(vtp + (size_t)(t_ * 32 + l31) * Sc \
                                              + (kb_) * 32 + c_ * 16 + hi * 8);   \
        f32x16 st;                                                             \
        _Pragma("unroll")                                                      \
        for (int r_ = 0; r_ < 16; r_++) st[r_] = 0.f;                          \
        _Pragma("unroll")                                                      \
        for (int kc_ = 0; kc_ < 4; kc_++)                                      \
            st = mfma32(KB_[kc_], qh[kc_], st);                                \
        if ((kb_) == brow) {                                                   \
            _Pragma("unroll")                                                  \
            for (int r_ = 0; r_ < 16; r_++) {                                  \
                int kvl_ = (r_ & 3) + 8 * (r_ >> 2) + 4 * hi;                  \
                if (kvl_ > l31) st[r_] = -1e30f;                               \
            }                                                                  \
        }                                                                      \
        float mx_;                                                             \
        {                                                                      \
            float t0 = fmaxf(st[0], st[1]),   t1 = fmaxf(st[2], st[3]);        \
            float t2 = fmaxf(st[4], st[5]),   t3 = fmaxf(st[6], st[7]);        \
            float t4 = fmaxf(st[8], st[9]),   t5 = fmaxf(st[10], st[11]);      \
            float t6 = fmaxf(st[12], st[13]), t7 = fmaxf(st[14], st[15]);      \
            t0 = fmaxf(t0, t1); t2 = fmaxf(t2, t3);                            \
            t4 = fmaxf(t4, t5); t6 = fmaxf(t6, t7);                            \
            mx_ = fmaxf(fmaxf(t0, t2), fmaxf(t4, t6));                         \
        }                                                                      \
        mx_ = fmaxf(mx_, __shfl_xor(mx_, 32));                                 \
        float mn_ = fmaxf(mrow, mx_);                                          \
        float al_ = __expf(mrow - mn_);                                        \
        mrow = mn_;                                                            \
        float p_[16];                                                          \
        _Pragma("unroll")                                                      \
        for (int r_ = 0; r_ < 16; r_++) p_[r_] = __expf(st[r_] - mn_);         \
        {                                                                      \
            float s0 = (p_[0] + p_[1]) + (p_[2] + p_[3]);                      \
            float s1 = (p_[4] + p_[5]) + (p_[6] + p_[7]);                      \
            float s2 = (p_[8] + p_[9]) + (p_[10] + p_[11]);                    \
            float s3 = (p_[12] + p_[13]) + (p_[14] + p_[15]);                  \
            lrow = lrow * al_ + ((s0 + s1) + (s2 + s3));                       \
        }                                                                      \
        ot0 *= al_; ot1 *= al_;                                                \
        unsigned int pb_[8], qb_[8];                                           \
        _Pragma("unroll")                                                      \
        for (int i_ = 0; i_ < 8; i_++)                                         \
            pb_[i_] = pack_f16(p_[2 * i_], p_[2 * i_ + 1]);                    \
        _Pragma("unroll")                                                      \
        for (int i_ = 0; i_ < 8; i_++)                                         \
            qb_[i_] = (unsigned int)__shfl_xor((int)pb_[i_], 32);              \
        UB b0_, b1_;                                                           \
        b0_.u[0] = hi ? qb_[2] : pb_[0]; b0_.u[1] = hi ? qb_[3] : pb_[1];      \
        b0_.u[2] = hi ? pb_[2] : qb_[0]; b0_.u[3] = hi ? pb_[3] : qb_[1];      \
        b1_.u[0] = hi ? qb_[6] : pb_[4]; b1_.u[1] = hi ? qb_[7] : pb_[5];      \
        b1_.u[2] = hi ? pb_[6] : qb_[4]; b1_.u[3] = hi ? pb_[7] : qb_[5];      \
        ot0 = mfma32(va_[0][0], b0_.v, ot0);                                   \
        ot0 = mfma32(va_[0][1], b1_.v, ot0);                                   \
        ot1 = mfma32(va_[1][0], b0_.v, ot1);                                   \
        ot1 = mfma32(va_[1][1], b1_.v, ot1);                                   \
    }                                                                          \
} while (0)

__global__ __launch_bounds__(128, 4) void k_attn(const float* __restrict__ Q,
                                                 const f16_t* __restrict__ KH,
                                                 const f16_t* __restrict__ VT,
                                                 const unsigned char* __restrict__ BM,
                                                 float* __restrict__ Out) {
    __shared__ float lds_o[64 * 33];
    __shared__ float lds_m[32];
    __shared__ float lds_l[32];

    const int qi   = 63 - (int)(blockIdx.x >> 5);   // heavy block-rows dispatch first
    const int bh   = blockIdx.x & 31;
    const int h    = bh & (Hc - 1);
    const int w    = threadIdx.x >> 6;
    const int lane = threadIdx.x & 63;
    const int l31  = lane & 31, hi = lane >> 5;

    const size_t bh_off = (size_t)bh * Sc * Dc;
    const float* q_ptr  = Q  + bh_off;
    const f16_t* khp    = KH + bh_off;
    const f16_t* vtp    = VT + bh_off;

    const int q0   = qi * 32;
    const int brow = qi;
    const unsigned char* bmrow = BM + ((size_t)h * NB + brow) * NB;
    const unsigned long long actmask = __ballot(bmrow[lane] != 0);

    // Q fragments (B-operand of S^T): lane holds Q[q0+l31][kc*16 + hi*8 + j]
    f16x8 qh[4];
    {
        const float* qr = q_ptr + (size_t)(q0 + l31) * Dc + hi * 8;
#pragma unroll
        for (int kc = 0; kc < 4; kc++) {
            f32x4 a = *(const f32x4*)(qr + kc * 16);
            f32x4 b = *(const f32x4*)(qr + kc * 16 + 4);
            float xs[8] = {a[0], a[1], a[2], a[3], b[0], b[1], b[2], b[3]};
#pragma unroll
            for (int j = 0; j < 8; j++) qh[kc][j] = (f16_t)xs[j];
        }
    }

    f32x16 ot0, ot1;
#pragma unroll
    for (int r = 0; r < 16; r++) { ot0[r] = 0.f; ot1[r] = 0.f; }
    float mrow = -INFINITY, lrow = 0.f;

    // this wave handles kb == w (mod 2), double-buffered
    f16x8 kbufA[4], kbufB[4];
    int ib = w;
    if (ib <= brow) KLOAD(kbufA, ib);
    while (ib <= brow) {
        if (ib + 2 <= brow) KLOAD(kbufB, ib + 2);
        STEP(kbufA, ib);
        ib += 2;
        if (ib > brow) break;
        if (ib + 2 <= brow) KLOAD(kbufA, ib + 2);
        STEP(kbufB, ib);
        ib += 2;
    }

    // ---- merge the two waves' partials (exact flash-decode merge) ----
    float lsum = lrow + __shfl_xor(lrow, 32);   // combine lane-half partial sums
    if (w == 1) {
#pragma unroll
        for (int r = 0; r < 16; r++) {
            int d0 = (r & 3) + 8 * (r >> 2) + 4 * hi;
            lds_o[d0 * 33 + l31]        = ot0[r];
            lds_o[(d0 + 32) * 33 + l31] = ot1[r];
        }
        if (hi == 0) { lds_m[l31] = mrow; lds_l[l31] = lsum; }
    }
    __syncthreads();
    if (w == 0) {
        float m1 = lds_m[l31], l1 = lds_l[l31];
        float mm = fmaxf(mrow, m1);
        float a0 = (mrow > -1e37f) ? __expf(mrow - mm) : 0.f;
        float a1 = (m1   > -1e37f) ? __expf(m1   - mm) : 0.f;
        float lt = lsum * a0 + l1 * a1;
        float inv = (lt > 0.f) ? (1.f / lt) : 0.f;
        float* op = Out + bh_off + (size_t)(q0 + l31) * Dc;
#pragma unroll
        for (int g = 0; g < 4; g++) {
            f32x4 w0, w1;
#pragma unroll
            for (int j = 0; j < 4; j++) {
                int r = g * 4 + j;
                int d0 = j + 8 * g + 4 * hi;
                w0[j] = (ot0[r] * a0 + lds_o[d0 * 33 + l31] * a1) * inv;
                w1[j] = (ot1[r] * a0 + lds_o[(d0 + 32) * 33 + l31] * a1) * inv;
            }
            *(f32x4*)(op + g * 8 + hi * 4)      = w0;
            *(f32x4*)(op + 32 + g * 8 + hi * 4) = w1;
        }
    }
}

extern "C" void kernel_launch(void* const* d_in, const int* in_sizes, int n_in,
                              void* d_out, int out_size, void* d_ws, size_t ws_size,
                              hipStream_t stream) {
    const float* Q    = (const float*)d_in[0];
    const float* K    = (const float*)d_in[1];
    const float* V    = (const float*)d_in[2];
    const float* bias = (const float*)d_in[3];
    const int*   mask = (const int*)d_in[4];
    float* out = (float*)d_out;

    char* ws = (char*)d_ws;
    f16_t* kh = (f16_t*)ws;                                    // 8 MiB
    f16_t* vt = (f16_t*)(ws + QKV_ELEMS * 2);                  // 8 MiB
    unsigned char* bm = (unsigned char*)(ws + QKV_ELEMS * 4);  // 64 KiB

    k_prep <<<4096, 256, 0, stream>>>(K, V, mask, bias, kh, vt, bm);
    k_attn <<<Bc * Hc * NB, 128, 0, stream>>>(Q, kh, vt, bm, out);
}